// Round 1
// baseline (183.164 us; speedup 1.0000x reference)
//
#include <hip/hip_runtime.h>
#include <math.h>

#define W128  128
#define NNODE 1024
#define NREL  12

// ws layout (float offsets)
#define OFF_S1T   0          // 128x128  s1t[w][j] = softmax(arg1_w, axis0)[j][w]
#define OFF_S2T   16384      // 128x128
#define OFF_OPW   32768      // 5x128    opwT[k][w]
#define OFF_WF    33408      // 128x12   wf[w][r]
#define OFF_WB    34944      // 128x12
#define OFF_ARG1  36480      // 128x1024
#define OFF_ARG2  167552     // 128x1024
#define OFF_PART  298624     // (12*MG) x 128 x 1024 partial chained

// ---------------- prep: all the small softmaxes ----------------
__global__ void k_prep(const float* __restrict__ a1w, const float* __restrict__ a2w,
                       const float* __restrict__ opww, const float* __restrict__ chw,
                       float* __restrict__ ws) {
    int i = threadIdx.x;  // 0..127
    // column softmax (axis 0) of arg1_w / arg2_w, stored transposed
    {
        float mx = -1e30f;
        for (int j = 0; j < W128; ++j) mx = fmaxf(mx, a1w[j * W128 + i]);
        float s = 0.f;
        for (int j = 0; j < W128; ++j) {
            float e = expf(a1w[j * W128 + i] - mx);
            ws[OFF_S1T + i * W128 + j] = e;
            s += e;
        }
        float inv = 1.0f / s;
        for (int j = 0; j < W128; ++j) ws[OFF_S1T + i * W128 + j] *= inv;
    }
    {
        float mx = -1e30f;
        for (int j = 0; j < W128; ++j) mx = fmaxf(mx, a2w[j * W128 + i]);
        float s = 0.f;
        for (int j = 0; j < W128; ++j) {
            float e = expf(a2w[j * W128 + i] - mx);
            ws[OFF_S2T + i * W128 + j] = e;
            s += e;
        }
        float inv = 1.0f / s;
        for (int j = 0; j < W128; ++j) ws[OFF_S2T + i * W128 + j] *= inv;
    }
    // op_weights row softmax (axis 1), stored transposed: opwT[k][w]
    {
        float v[5], mx = -1e30f;
        for (int k = 0; k < 5; ++k) { v[k] = opww[i * 5 + k]; mx = fmaxf(mx, v[k]); }
        float s = 0.f;
        for (int k = 0; k < 5; ++k) { v[k] = expf(v[k] - mx); s += v[k]; }
        float inv = 1.0f / s;
        for (int k = 0; k < 5; ++k) ws[OFF_OPW + k * W128 + i] = v[k] * inv;
    }
    // chain_weights row softmax over 24 -> wf (first 12), wb (last 12)
    {
        float v[24], mx = -1e30f;
        for (int k = 0; k < 24; ++k) { v[k] = chw[i * 24 + k]; mx = fmaxf(mx, v[k]); }
        float s = 0.f;
        for (int k = 0; k < 24; ++k) { v[k] = expf(v[k] - mx); s += v[k]; }
        float inv = 1.0f / s;
        for (int k = 0; k < 12; ++k) ws[OFF_WF + i * NREL + k] = v[k] * inv;
        for (int k = 0; k < 12; ++k) ws[OFF_WB + i * NREL + k] = v[12 + k] * inv;
    }
}

// ---------------- arg1/arg2 = smT @ inputs ----------------
__global__ __launch_bounds__(256) void k_args(const float* __restrict__ inputs,
                                              float* __restrict__ ws) {
    int w = blockIdx.y;
    int n = blockIdx.x * 256 + threadIdx.x;
    const float* s1 = ws + OFF_S1T + w * W128;
    const float* s2 = ws + OFF_S2T + w * W128;
    float a1 = 0.f, a2 = 0.f;
    for (int j = 0; j < W128; ++j) {
        float in = inputs[j * NNODE + n];
        a1 = fmaf(s1[j], in, a1);
        a2 = fmaf(s2[j], in, a2);
    }
    ws[OFF_ARG1 + w * NNODE + n] = a1;
    ws[OFF_ARG2 + w * NNODE + n] = a2;
}

// ---------------- chain partials ----------------
// block = (c-tile ci of 64 cols, slice s = r*MG+mg). Thread: tw=tid>>4 owns 8 w,
// tc=tid&15 owns 4 c. accF = sum_a x[w,a] db[r,a,c]; accB = sum_b x[w,b] db[r,c,b].
// partial[s][w][c] = wf[w,r]*accF + wb[w,r]*accB  (deterministic split-K, no atomics)
__global__ __launch_bounds__(256) void k_chain(const float* __restrict__ db,
                                               const float* __restrict__ ws,
                                               float* __restrict__ part,
                                               int MG, int mlen) {
    __shared__ __align__(16) float lx[W128 * 33]; // [w][m] stride 33
    __shared__ __align__(16) float lf[32 * 68];   // [m][c] stride 68 (16B-aligned rows)
    __shared__ __align__(16) float lb[64 * 33];   // [c][m] stride 33
    const float* arg2 = ws + OFF_ARG2;
    const float* wf   = ws + OFF_WF;
    const float* wb   = ws + OFF_WB;
    int tid = threadIdx.x;
    int tw = tid >> 4;   // 0..15 -> w = tw*8..+7
    int tc = tid & 15;   // 0..15 -> c = c0 + tc*4..+3
    int c0 = blockIdx.x * 64;
    int s  = blockIdx.y;
    int r  = s / MG;
    int mg = s - r * MG;
    int mbase0 = mg * mlen;

    float accF[8][4];
    float accB[8][4];
#pragma unroll
    for (int i = 0; i < 8; ++i)
#pragma unroll
        for (int q = 0; q < 4; ++q) { accF[i][q] = 0.f; accB[i][q] = 0.f; }

    int nchunks = mlen >> 5;
    for (int ch = 0; ch < nchunks; ++ch) {
        int mb = mbase0 + ch * 32;
        __syncthreads();
        // stage arg2 slab [128 w][32 m]
        for (int idx = tid; idx < W128 * 32; idx += 256) {
            int w = idx >> 5, m = idx & 31;
            lx[w * 33 + m] = arg2[w * NNODE + mb + m];
        }
        // stage fwd db tile: db[r][mb+m][c0+cc]  (rows m, cols c)
        for (int idx = tid; idx < 32 * 64; idx += 256) {
            int m = idx >> 6, cc = idx & 63;
            lf[m * 68 + cc] = db[((size_t)r * NNODE + (mb + m)) * NNODE + c0 + cc];
        }
        // stage bwd db tile: db[r][c0+cc][mb+m]  (rows c, cols m)
        for (int idx = tid; idx < 64 * 32; idx += 256) {
            int cc = idx >> 5, m = idx & 31;
            lb[cc * 33 + m] = db[((size_t)r * NNODE + c0 + cc) * NNODE + mb + m];
        }
        __syncthreads();
#pragma unroll 2
        for (int m = 0; m < 32; ++m) {
            float xv[8], fv[4], bv[4];
#pragma unroll
            for (int i = 0; i < 8; ++i) xv[i] = lx[(tw * 8 + i) * 33 + m];
#pragma unroll
            for (int q = 0; q < 4; ++q) fv[q] = lf[m * 68 + tc * 4 + q];
#pragma unroll
            for (int q = 0; q < 4; ++q) bv[q] = lb[(tc * 4 + q) * 33 + m];
#pragma unroll
            for (int i = 0; i < 8; ++i)
#pragma unroll
                for (int q = 0; q < 4; ++q) {
                    accF[i][q] = fmaf(xv[i], fv[q], accF[i][q]);
                    accB[i][q] = fmaf(xv[i], bv[q], accB[i][q]);
                }
        }
    }
    // epilogue: apply per-(w,r) chain weights, write partial slice
#pragma unroll
    for (int i = 0; i < 8; ++i) {
        int w = tw * 8 + i;
        float wfv = wf[w * NREL + r];
        float wbv = wb[w * NREL + r];
        float4 o;
        o.x = wfv * accF[i][0] + wbv * accB[i][0];
        o.y = wfv * accF[i][1] + wbv * accB[i][1];
        o.z = wfv * accF[i][2] + wbv * accB[i][2];
        o.w = wfv * accF[i][3] + wbv * accB[i][3];
        *(float4*)&part[((size_t)s * W128 + w) * NNODE + c0 + tc * 4] = o;
    }
}

// ---------------- reduce slices + final op combine ----------------
__global__ __launch_bounds__(256) void k_reduce(const float* __restrict__ ws,
                                                const float* __restrict__ part,
                                                float* __restrict__ out, int S) {
    int e = blockIdx.x * 256 + threadIdx.x;  // 0..131071
    int w = e >> 10;
    float ch = 0.f;
    for (int s2 = 0; s2 < S; ++s2) ch += part[(size_t)s2 * (W128 * NNODE) + e];
    float a1 = ws[OFF_ARG1 + e];
    float a2 = ws[OFF_ARG2 + e];
    float o0 = ws[OFF_OPW + 0 * W128 + w];
    float o1 = ws[OFF_OPW + 1 * W128 + w];
    float o2 = ws[OFF_OPW + 2 * W128 + w];
    float o3 = ws[OFF_OPW + 3 * W128 + w];
    float o4 = ws[OFF_OPW + 4 * W128 + w];
    float a12 = a1 * a2;
    out[e] = o0 * a2 + o1 * a12 + o2 * (a1 + a2 - a12)
           + o3 * (1.0f - expf(-ch)) + o4 * (1.0f - a1);
}

extern "C" void kernel_launch(void* const* d_in, const int* in_sizes, int n_in,
                              void* d_out, int out_size, void* d_ws, size_t ws_size,
                              hipStream_t stream) {
    const float* inputs = (const float*)d_in[0];
    const float* db     = (const float*)d_in[1];
    const float* a1w    = (const float*)d_in[2];
    const float* a2w    = (const float*)d_in[3];
    const float* opww   = (const float*)d_in[4];
    const float* chw    = (const float*)d_in[5];
    float* ws  = (float*)d_ws;
    float* out = (float*)d_out;

    // split-K factor: 4 if ws can hold 48 partial slices (26.4 MB), else 1 (7.5 MB)
    int MG = 4;
    size_t need4 = ((size_t)OFF_PART + (size_t)NREL * 4 * W128 * NNODE) * sizeof(float);
    if (ws_size < need4) MG = 1;
    int mlen = NNODE / MG;

    hipLaunchKernelGGL(k_prep, dim3(1), dim3(128), 0, stream, a1w, a2w, opww, chw, ws);
    hipLaunchKernelGGL(k_args, dim3(4, 128), dim3(256), 0, stream, inputs, ws);
    hipLaunchKernelGGL(k_chain, dim3(16, NREL * MG), dim3(256), 0, stream,
                       db, ws, ws + OFF_PART, MG, mlen);
    hipLaunchKernelGGL(k_reduce, dim3(512), dim3(256), 0, stream,
                       ws, ws + OFF_PART, out, NREL * MG);
}

// Round 2
// 83.220 us; speedup vs baseline: 2.2010x; 2.2010x over previous
//
#include <hip/hip_runtime.h>
#include <math.h>

#define W128  128
#define NNODE 1024
#define NREL  12
#define MG    16      // split-K groups
#define KC    64      // K-chunk per block = NNODE/MG

// ws layout (float offsets)
#define OFF_S1T   0         // 128x128
#define OFF_S2T   16384     // 128x128
#define OFF_OPW   32768     // 5x128
#define OFF_WF    33408     // 128x12
#define OFF_WB    34944     // 128x12
#define OFF_ARG1  36480     // 128x1024 f32
#define OFF_ARG2  167552    // 128x1024 f32
#define OFF_ARG2B 298624    // 128x1024 bf16 (65536 floats worth)
#define OFF_PART  364160    // MG x 128 x 1024 f32

typedef short bf16x8 __attribute__((ext_vector_type(8)));
typedef float f32x4  __attribute__((ext_vector_type(4)));

// ---------------- prep: softmaxes, 3 parallel blocks ----------------
__global__ void k_prep(const float* __restrict__ a1w, const float* __restrict__ a2w,
                       const float* __restrict__ opww, const float* __restrict__ chw,
                       float* __restrict__ ws) {
    int b = blockIdx.x;
    int i = threadIdx.x;  // 0..127
    if (b == 0 || b == 1) {
        const float* src = (b == 0) ? a1w : a2w;
        float* dst = ws + ((b == 0) ? OFF_S1T : OFF_S2T);
        float mx = -1e30f;
        for (int j = 0; j < W128; ++j) mx = fmaxf(mx, src[j * W128 + i]);
        float s = 0.f;
        for (int j = 0; j < W128; ++j) {
            float e = expf(src[j * W128 + i] - mx);
            dst[i * W128 + j] = e;
            s += e;
        }
        float inv = 1.0f / s;
        for (int j = 0; j < W128; ++j) dst[i * W128 + j] *= inv;
    } else {
        // op_weights row softmax -> opwT[k][w]
        float v[5], mx = -1e30f;
        for (int k = 0; k < 5; ++k) { v[k] = opww[i * 5 + k]; mx = fmaxf(mx, v[k]); }
        float s = 0.f;
        for (int k = 0; k < 5; ++k) { v[k] = expf(v[k] - mx); s += v[k]; }
        float inv = 1.0f / s;
        for (int k = 0; k < 5; ++k) ws[OFF_OPW + k * W128 + i] = v[k] * inv;
        // chain_weights row softmax over 24 -> wf, wb
        float u[24]; mx = -1e30f;
        for (int k = 0; k < 24; ++k) { u[k] = chw[i * 24 + k]; mx = fmaxf(mx, u[k]); }
        s = 0.f;
        for (int k = 0; k < 24; ++k) { u[k] = expf(u[k] - mx); s += u[k]; }
        inv = 1.0f / s;
        for (int k = 0; k < 12; ++k) ws[OFF_WF + i * NREL + k] = u[k] * inv;
        for (int k = 0; k < 12; ++k) ws[OFF_WB + i * NREL + k] = u[12 + k] * inv;
    }
}

// ---------------- arg1/arg2 = smT @ inputs (+ bf16 copy of arg2) -------------
__global__ __launch_bounds__(256) void k_args(const float* __restrict__ inputs,
                                              float* __restrict__ ws,
                                              short* __restrict__ x2b) {
    int w = blockIdx.y;
    int n = blockIdx.x * 256 + threadIdx.x;
    const float* s1 = ws + OFF_S1T + w * W128;
    const float* s2 = ws + OFF_S2T + w * W128;
    float a1 = 0.f, a2 = 0.f;
    for (int j = 0; j < W128; ++j) {
        float in = inputs[j * NNODE + n];
        a1 = fmaf(s1[j], in, a1);
        a2 = fmaf(s2[j], in, a2);
    }
    ws[OFF_ARG1 + w * NNODE + n] = a1;
    ws[OFF_ARG2 + w * NNODE + n] = a2;
    x2b[w * NNODE + n] = (short)(__float_as_uint(a2) >> 16);  // trunc bf16 (chain only)
}

// ---------------- chain via MFMA ----------------
// Block: c-tile 64 (blockIdx.x of 16), K-chunk 64 (blockIdx.y = mg of 16), loop r.
// 512 threads = 8 waves in 4x2: wm=wid>>1 owns 32 rows(w), wn=wid&1 owns 32 cols(c).
// acc folds wf/wb per-r in registers -> part[mg][w][c] only.
__global__ __launch_bounds__(512) void k_chain_mfma(const float* __restrict__ db,
                                                    const float* __restrict__ ws,
                                                    const short* __restrict__ x2b,
                                                    float* __restrict__ part) {
    __shared__ float dfs[64 * 65];                 // fwd tile f32 [k][c] stride 65
    __shared__ __align__(16) short dbs[64 * 72];   // bwd tile bf16 [c][k] stride 72
    const float* wf = ws + OFF_WF;
    const float* wb = ws + OFF_WB;

    int tid = threadIdx.x;
    int l   = tid & 63, wid = tid >> 6;
    int wm  = wid >> 1, wn = wid & 1;
    int l16 = l & 15,  lq = l >> 4;
    int c0  = blockIdx.x * 64;
    int mg  = blockIdx.y;
    int kb  = mg * KC;
    int cwl = wn * 32;          // wave col offset within tile
    int c0w = c0 + cwl;

    // A-frags (X = arg2 bf16), loaded once, reused for all r
    bf16x8 afr[2][2];
#pragma unroll
    for (int mi = 0; mi < 2; ++mi)
#pragma unroll
        for (int ks = 0; ks < 2; ++ks) {
            int w = wm * 32 + mi * 16 + l16;
            afr[mi][ks] = *(const bf16x8*)&x2b[w * NNODE + kb + ks * 32 + lq * 8];
        }

    f32x4 acc[2][2];
#pragma unroll
    for (int mi = 0; mi < 2; ++mi)
#pragma unroll
        for (int ni = 0; ni < 2; ++ni) acc[mi][ni] = (f32x4){0.f, 0.f, 0.f, 0.f};

#pragma unroll 1
    for (int r = 0; r < NREL; ++r) {
        const float* dbr = db + (size_t)r * NNODE * NNODE;
        // stage fwd tile: db[r][kb+k][c0+c] -> dfs[k][c]  (f32, coalesced 256B rows)
        const float* fbase = dbr + (size_t)kb * NNODE + c0;
#pragma unroll
        for (int u = 0; u < 8; ++u) {
            int idx = tid + u * 512;
            int k = idx >> 6, c = idx & 63;
            dfs[k * 65 + c] = fbase[k * NNODE + c];
        }
        // stage bwd tile: db[r][c0+c][kb+2k2..] -> dbs[c][2k2] bf16 packed
        const float* bbase = dbr + (size_t)c0 * NNODE + kb;
#pragma unroll
        for (int u = 0; u < 4; ++u) {
            int idx = tid + u * 512;
            int c = idx >> 5, k2 = idx & 31;
            float2 v = *(const float2*)&bbase[c * NNODE + 2 * k2];
            unsigned int pk = (__float_as_uint(v.y) & 0xFFFF0000u) |
                              (__float_as_uint(v.x) >> 16);
            *(unsigned int*)&dbs[c * 72 + 2 * k2] = pk;
        }
        __syncthreads();

        f32x4 aF[2][2], aB[2][2];
#pragma unroll
        for (int mi = 0; mi < 2; ++mi)
#pragma unroll
            for (int ni = 0; ni < 2; ++ni) {
                aF[mi][ni] = (f32x4){0.f, 0.f, 0.f, 0.f};
                aB[mi][ni] = (f32x4){0.f, 0.f, 0.f, 0.f};
            }

#pragma unroll
        for (int ks = 0; ks < 2; ++ks) {
            bf16x8 bfr[2], bbr[2];
#pragma unroll
            for (int ni = 0; ni < 2; ++ni) {
                // fwd B-frag: 8 strided f32 reads (2-way max bank alias), pack bf16
                int col  = cwl + ni * 16 + l16;
                int rowb = ks * 32 + lq * 8;
                float f0 = dfs[(rowb + 0) * 65 + col];
                float f1 = dfs[(rowb + 1) * 65 + col];
                float f2 = dfs[(rowb + 2) * 65 + col];
                float f3 = dfs[(rowb + 3) * 65 + col];
                float f4 = dfs[(rowb + 4) * 65 + col];
                float f5 = dfs[(rowb + 5) * 65 + col];
                float f6 = dfs[(rowb + 6) * 65 + col];
                float f7 = dfs[(rowb + 7) * 65 + col];
                int4 pk;
                pk.x = (int)((__float_as_uint(f1) & 0xFFFF0000u) | (__float_as_uint(f0) >> 16));
                pk.y = (int)((__float_as_uint(f3) & 0xFFFF0000u) | (__float_as_uint(f2) >> 16));
                pk.z = (int)((__float_as_uint(f5) & 0xFFFF0000u) | (__float_as_uint(f4) >> 16));
                pk.w = (int)((__float_as_uint(f7) & 0xFFFF0000u) | (__float_as_uint(f6) >> 16));
                bfr[ni] = __builtin_bit_cast(bf16x8, pk);
                // bwd B-frag: contiguous bf16, one b128
                bbr[ni] = *(const bf16x8*)&dbs[(cwl + ni * 16 + l16) * 72 + ks * 32 + lq * 8];
            }
#pragma unroll
            for (int mi = 0; mi < 2; ++mi)
#pragma unroll
                for (int ni = 0; ni < 2; ++ni) {
                    aF[mi][ni] = __builtin_amdgcn_mfma_f32_16x16x32_bf16(
                        afr[mi][ks], bfr[ni], aF[mi][ni], 0, 0, 0);
                    aB[mi][ni] = __builtin_amdgcn_mfma_f32_16x16x32_bf16(
                        afr[mi][ks], bbr[ni], aB[mi][ni], 0, 0, 0);
                }
        }
        __syncthreads();

        // fold per-r chain weights into running accumulator
#pragma unroll
        for (int mi = 0; mi < 2; ++mi)
#pragma unroll
            for (int v = 0; v < 4; ++v) {
                int w = wm * 32 + mi * 16 + lq * 4 + v;
                float wfv = wf[w * NREL + r];
                float wbv = wb[w * NREL + r];
#pragma unroll
                for (int ni = 0; ni < 2; ++ni)
                    acc[mi][ni][v] += wfv * aF[mi][ni][v] + wbv * aB[mi][ni][v];
            }
    }

    // write partial slice: part[mg][w][c]
#pragma unroll
    for (int mi = 0; mi < 2; ++mi)
#pragma unroll
        for (int ni = 0; ni < 2; ++ni) {
            int c = c0w + ni * 16 + l16;
#pragma unroll
            for (int v = 0; v < 4; ++v) {
                int w = wm * 32 + mi * 16 + lq * 4 + v;
                part[((size_t)mg * W128 + w) * NNODE + c] = acc[mi][ni][v];
            }
        }
}

// ---------------- reduce MG slices + final op combine ----------------
__global__ __launch_bounds__(256) void k_reduce(const float* __restrict__ ws,
                                                const float* __restrict__ part,
                                                float* __restrict__ out) {
    int e = blockIdx.x * 256 + threadIdx.x;  // 0..131071
    int w = e >> 10;
    float ch = 0.f;
#pragma unroll
    for (int s = 0; s < MG; ++s) ch += part[(size_t)s * (W128 * NNODE) + e];
    float a1 = ws[OFF_ARG1 + e];
    float a2 = ws[OFF_ARG2 + e];
    float o0 = ws[OFF_OPW + 0 * W128 + w];
    float o1 = ws[OFF_OPW + 1 * W128 + w];
    float o2 = ws[OFF_OPW + 2 * W128 + w];
    float o3 = ws[OFF_OPW + 3 * W128 + w];
    float o4 = ws[OFF_OPW + 4 * W128 + w];
    float a12 = a1 * a2;
    out[e] = o0 * a2 + o1 * a12 + o2 * (a1 + a2 - a12)
           + o3 * (1.0f - expf(-ch)) + o4 * (1.0f - a1);
}

extern "C" void kernel_launch(void* const* d_in, const int* in_sizes, int n_in,
                              void* d_out, int out_size, void* d_ws, size_t ws_size,
                              hipStream_t stream) {
    const float* inputs = (const float*)d_in[0];
    const float* db     = (const float*)d_in[1];
    const float* a1w    = (const float*)d_in[2];
    const float* a2w    = (const float*)d_in[3];
    const float* opww   = (const float*)d_in[4];
    const float* chw    = (const float*)d_in[5];
    float* ws  = (float*)d_ws;
    float* out = (float*)d_out;
    short* x2b = (short*)(ws + OFF_ARG2B);
    float* part = ws + OFF_PART;

    hipLaunchKernelGGL(k_prep, dim3(3), dim3(128), 0, stream, a1w, a2w, opww, chw, ws);
    hipLaunchKernelGGL(k_args, dim3(4, 128), dim3(256), 0, stream, inputs, ws, x2b);
    hipLaunchKernelGGL(k_chain_mfma, dim3(16, MG), dim3(512), 0, stream,
                       db, ws, x2b, part);
    hipLaunchKernelGGL(k_reduce, dim3(512), dim3(256), 0, stream, ws, part, out);
}

// Round 8
// 53.857 us; speedup vs baseline: 3.4010x; 1.5452x over previous
//
#include <hip/hip_runtime.h>
#include <math.h>

#define W128  128
#define NNODE 1024
#define NREL  12
#define MG    16      // split-K groups
#define KC    64      // K-chunk per block = NNODE/MG

// ws layout (float offsets)
#define OFF_S1T   0         // 128x128
#define OFF_S2T   16384     // 128x128
#define OFF_OPW   32768     // 5x128
#define OFF_WF    33408     // 128x12
#define OFF_WB    34944     // 128x12
#define OFF_ARG1  36480     // 128x1024 f32
#define OFF_ARG2  167552    // 128x1024 f32
#define OFF_ARG2B 298624    // 128x1024 bf16 (65536 floats worth)
#define OFF_PART  364160    // MG x 128 x 1024 f32

typedef short bf16x8 __attribute__((ext_vector_type(8)));
typedef float f32x4  __attribute__((ext_vector_type(4)));

// ---------------- prep: softmaxes, fully parallel ----------------
// blocks 0..127:  column softmax of a1w, column = bid      -> s1t[col][*]
// blocks 128..255: column softmax of a2w, column = bid-128 -> s2t[col][*]
// block 256: op_weights (5-wide) + chain_weights (24-wide) row softmaxes
__global__ __launch_bounds__(128) void k_prep(const float* __restrict__ a1w,
                                              const float* __restrict__ a2w,
                                              const float* __restrict__ opww,
                                              const float* __restrict__ chw,
                                              float* __restrict__ ws) {
    __shared__ float wred[2];
    int b = blockIdx.x;
    int j = threadIdx.x;  // 0..127
    if (b < 256) {
        int col = b & 127;
        const float* src = (b < 128) ? a1w : a2w;
        float* dst = ws + ((b < 128) ? OFF_S1T : OFF_S2T);
        float v = src[j * W128 + col];
        // max over 128 threads: wave butterfly then 2-wave combine
        float m = v;
#pragma unroll
        for (int off = 32; off; off >>= 1) m = fmaxf(m, __shfl_xor(m, off));
        if ((j & 63) == 0) wred[j >> 6] = m;
        __syncthreads();
        m = fmaxf(wred[0], wred[1]);
        float e = expf(v - m);
        float s = e;
#pragma unroll
        for (int off = 32; off; off >>= 1) s += __shfl_xor(s, off);
        __syncthreads();   // reuse wred safely
        if ((j & 63) == 0) wred[j >> 6] = s;
        __syncthreads();
        s = wred[0] + wred[1];
        dst[col * W128 + j] = e / s;
    } else {
        int i = j;
        // op_weights row softmax -> opwT[k][w]
        float v[5], mx = -1e30f;
        for (int k = 0; k < 5; ++k) { v[k] = opww[i * 5 + k]; mx = fmaxf(mx, v[k]); }
        float s = 0.f;
        for (int k = 0; k < 5; ++k) { v[k] = expf(v[k] - mx); s += v[k]; }
        float inv = 1.0f / s;
        for (int k = 0; k < 5; ++k) ws[OFF_OPW + k * W128 + i] = v[k] * inv;
        // chain_weights row softmax over 24 -> wf, wb
        float u[24]; mx = -1e30f;
        for (int k = 0; k < 24; ++k) { u[k] = chw[i * 24 + k]; mx = fmaxf(mx, u[k]); }
        s = 0.f;
        for (int k = 0; k < 24; ++k) { u[k] = expf(u[k] - mx); s += u[k]; }
        inv = 1.0f / s;
        for (int k = 0; k < 12; ++k) ws[OFF_WF + i * NREL + k] = u[k] * inv;
        for (int k = 0; k < 12; ++k) ws[OFF_WB + i * NREL + k] = u[12 + k] * inv;
    }
}

// ---------------- arg1/arg2 = smT @ inputs (+ bf16 copy of arg2) -------------
__global__ __launch_bounds__(256) void k_args(const float* __restrict__ inputs,
                                              float* __restrict__ ws,
                                              short* __restrict__ x2b) {
    int w = blockIdx.y;
    int n = blockIdx.x * 256 + threadIdx.x;
    const float* s1 = ws + OFF_S1T + w * W128;
    const float* s2 = ws + OFF_S2T + w * W128;
    float a1 = 0.f, a2 = 0.f;
    for (int j = 0; j < W128; ++j) {
        float in = inputs[j * NNODE + n];
        a1 = fmaf(s1[j], in, a1);
        a2 = fmaf(s2[j], in, a2);
    }
    ws[OFF_ARG1 + w * NNODE + n] = a1;
    ws[OFF_ARG2 + w * NNODE + n] = a2;
    x2b[w * NNODE + n] = (short)(__float_as_uint(a2) >> 16);  // trunc bf16 (chain only)
}

// ---------------- chain via MFMA ----------------
// Block: c-tile 64 (blockIdx.x of 16), K-chunk 64 (blockIdx.y = mg of 16), loop r.
// 512 threads = 8 waves in 4x2: wm=wid>>1 owns 32 rows(w), wn=wid&1 owns 32 cols(c).
// acc folds wf/wb per-r in registers -> part[mg][w][c] only.
__global__ __launch_bounds__(512) void k_chain_mfma(const float* __restrict__ db,
                                                    const float* __restrict__ ws,
                                                    const short* __restrict__ x2b,
                                                    float* __restrict__ part) {
    __shared__ float dfs[64 * 65];                 // fwd tile f32 [k][c] stride 65
    __shared__ __align__(16) short dbs[64 * 72];   // bwd tile bf16 [c][k] stride 72
    const float* wf = ws + OFF_WF;
    const float* wb = ws + OFF_WB;

    int tid = threadIdx.x;
    int l   = tid & 63, wid = tid >> 6;
    int wm  = wid >> 1, wn = wid & 1;
    int l16 = l & 15,  lq = l >> 4;
    int c0  = blockIdx.x * 64;
    int mg  = blockIdx.y;
    int kb  = mg * KC;
    int cwl = wn * 32;          // wave col offset within tile
    int c0w = c0 + cwl;

    // A-frags (X = arg2 bf16), loaded once, reused for all r
    bf16x8 afr[2][2];
#pragma unroll
    for (int mi = 0; mi < 2; ++mi)
#pragma unroll
        for (int ks = 0; ks < 2; ++ks) {
            int w = wm * 32 + mi * 16 + l16;
            afr[mi][ks] = *(const bf16x8*)&x2b[w * NNODE + kb + ks * 32 + lq * 8];
        }

    f32x4 acc[2][2];
#pragma unroll
    for (int mi = 0; mi < 2; ++mi)
#pragma unroll
        for (int ni = 0; ni < 2; ++ni) acc[mi][ni] = (f32x4){0.f, 0.f, 0.f, 0.f};

#pragma unroll 1
    for (int r = 0; r < NREL; ++r) {
        const float* dbr = db + (size_t)r * NNODE * NNODE;
        // stage fwd tile: db[r][kb+k][c0+c] -> dfs[k][c]  (f32, coalesced 256B rows)
        const float* fbase = dbr + (size_t)kb * NNODE + c0;
#pragma unroll
        for (int u = 0; u < 8; ++u) {
            int idx = tid + u * 512;
            int k = idx >> 6, c = idx & 63;
            dfs[k * 65 + c] = fbase[k * NNODE + c];
        }
        // stage bwd tile: db[r][c0+c][kb+2k2..] -> dbs[c][2k2] bf16 packed
        const float* bbase = dbr + (size_t)c0 * NNODE + kb;
#pragma unroll
        for (int u = 0; u < 4; ++u) {
            int idx = tid + u * 512;
            int c = idx >> 5, k2 = idx & 31;
            float2 v = *(const float2*)&bbase[c * NNODE + 2 * k2];
            unsigned int pk = (__float_as_uint(v.y) & 0xFFFF0000u) |
                              (__float_as_uint(v.x) >> 16);
            *(unsigned int*)&dbs[c * 72 + 2 * k2] = pk;
        }
        __syncthreads();

        f32x4 aF[2][2], aB[2][2];
#pragma unroll
        for (int mi = 0; mi < 2; ++mi)
#pragma unroll
            for (int ni = 0; ni < 2; ++ni) {
                aF[mi][ni] = (f32x4){0.f, 0.f, 0.f, 0.f};
                aB[mi][ni] = (f32x4){0.f, 0.f, 0.f, 0.f};
            }

#pragma unroll
        for (int ks = 0; ks < 2; ++ks) {
            bf16x8 bfr[2], bbr[2];
#pragma unroll
            for (int ni = 0; ni < 2; ++ni) {
                // fwd B-frag: 8 strided f32 reads (2-way max bank alias), pack bf16
                int col  = cwl + ni * 16 + l16;
                int rowb = ks * 32 + lq * 8;
                float f0 = dfs[(rowb + 0) * 65 + col];
                float f1 = dfs[(rowb + 1) * 65 + col];
                float f2 = dfs[(rowb + 2) * 65 + col];
                float f3 = dfs[(rowb + 3) * 65 + col];
                float f4 = dfs[(rowb + 4) * 65 + col];
                float f5 = dfs[(rowb + 5) * 65 + col];
                float f6 = dfs[(rowb + 6) * 65 + col];
                float f7 = dfs[(rowb + 7) * 65 + col];
                int4 pk;
                pk.x = (int)((__float_as_uint(f1) & 0xFFFF0000u) | (__float_as_uint(f0) >> 16));
                pk.y = (int)((__float_as_uint(f3) & 0xFFFF0000u) | (__float_as_uint(f2) >> 16));
                pk.z = (int)((__float_as_uint(f5) & 0xFFFF0000u) | (__float_as_uint(f4) >> 16));
                pk.w = (int)((__float_as_uint(f7) & 0xFFFF0000u) | (__float_as_uint(f6) >> 16));
                bfr[ni] = __builtin_bit_cast(bf16x8, pk);
                // bwd B-frag: contiguous bf16, one b128
                bbr[ni] = *(const bf16x8*)&dbs[(cwl + ni * 16 + l16) * 72 + ks * 32 + lq * 8];
            }
#pragma unroll
            for (int mi = 0; mi < 2; ++mi)
#pragma unroll
                for (int ni = 0; ni < 2; ++ni) {
                    aF[mi][ni] = __builtin_amdgcn_mfma_f32_16x16x32_bf16(
                        afr[mi][ks], bfr[ni], aF[mi][ni], 0, 0, 0);
                    aB[mi][ni] = __builtin_amdgcn_mfma_f32_16x16x32_bf16(
                        afr[mi][ks], bbr[ni], aB[mi][ni], 0, 0, 0);
                }
        }
        __syncthreads();

        // fold per-r chain weights into running accumulator
#pragma unroll
        for (int mi = 0; mi < 2; ++mi)
#pragma unroll
            for (int v = 0; v < 4; ++v) {
                int w = wm * 32 + mi * 16 + lq * 4 + v;
                float wfv = wf[w * NREL + r];
                float wbv = wb[w * NREL + r];
#pragma unroll
                for (int ni = 0; ni < 2; ++ni)
                    acc[mi][ni][v] += wfv * aF[mi][ni][v] + wbv * aB[mi][ni][v];
            }
    }

    // write partial slice: part[mg][w][c]
#pragma unroll
    for (int mi = 0; mi < 2; ++mi)
#pragma unroll
        for (int ni = 0; ni < 2; ++ni) {
            int c = c0w + ni * 16 + l16;
#pragma unroll
            for (int v = 0; v < 4; ++v) {
                int w = wm * 32 + mi * 16 + lq * 4 + v;
                part[((size_t)mg * W128 + w) * NNODE + c] = acc[mi][ni][v];
            }
        }
}

// ---------------- reduce MG slices + final op combine ----------------
__global__ __launch_bounds__(256) void k_reduce(const float* __restrict__ ws,
                                                const float* __restrict__ part,
                                                float* __restrict__ out) {
    int e = blockIdx.x * 256 + threadIdx.x;  // 0..131071
    int w = e >> 10;
    float ch = 0.f;
#pragma unroll
    for (int s = 0; s < MG; ++s) ch += part[(size_t)s * (W128 * NNODE) + e];
    float a1 = ws[OFF_ARG1 + e];
    float a2 = ws[OFF_ARG2 + e];
    float o0 = ws[OFF_OPW + 0 * W128 + w];
    float o1 = ws[OFF_OPW + 1 * W128 + w];
    float o2 = ws[OFF_OPW + 2 * W128 + w];
    float o3 = ws[OFF_OPW + 3 * W128 + w];
    float o4 = ws[OFF_OPW + 4 * W128 + w];
    float a12 = a1 * a2;
    out[e] = o0 * a2 + o1 * a12 + o2 * (a1 + a2 - a12)
           + o3 * (1.0f - expf(-ch)) + o4 * (1.0f - a1);
}

extern "C" void kernel_launch(void* const* d_in, const int* in_sizes, int n_in,
                              void* d_out, int out_size, void* d_ws, size_t ws_size,
                              hipStream_t stream) {
    const float* inputs = (const float*)d_in[0];
    const float* db     = (const float*)d_in[1];
    const float* a1w    = (const float*)d_in[2];
    const float* a2w    = (const float*)d_in[3];
    const float* opww   = (const float*)d_in[4];
    const float* chw    = (const float*)d_in[5];
    float* ws  = (float*)d_ws;
    float* out = (float*)d_out;
    short* x2b = (short*)(ws + OFF_ARG2B);
    float* part = ws + OFF_PART;

    hipLaunchKernelGGL(k_prep, dim3(257), dim3(128), 0, stream, a1w, a2w, opww, chw, ws);
    hipLaunchKernelGGL(k_args, dim3(4, 128), dim3(256), 0, stream, inputs, ws, x2b);
    hipLaunchKernelGGL(k_chain_mfma, dim3(16, MG), dim3(512), 0, stream,
                       db, ws, x2b, part);
    hipLaunchKernelGGL(k_reduce, dim3(512), dim3(256), 0, stream, ws, part, out);
}

// Round 9
// 47.134 us; speedup vs baseline: 3.8860x; 1.1426x over previous
//
#include <hip/hip_runtime.h>
#include <math.h>

#define W128  128
#define NNODE 1024
#define NREL  12

// ws layout (float offsets)
#define OFF_S1T   0         // 128x128
#define OFF_S2T   16384     // 128x128
#define OFF_OPW   32768     // 5x128
#define OFF_WF    33408     // 128x12
#define OFF_WB    34944     // 128x12
#define OFF_ARG1  36480     // 128x1024 f32
#define OFF_ARG2  167552    // 128x1024 f32
#define OFF_ARG2B 298624    // 128x1024 bf16
#define OFF_PART  364160    // partF 16x128x1024 bf16, then partB same

typedef short bf16x8 __attribute__((ext_vector_type(8)));
typedef short short4v __attribute__((ext_vector_type(4)));
typedef float f32x4  __attribute__((ext_vector_type(4)));

__device__ __forceinline__ short bf16t(float x) {
    return (short)(__float_as_uint(x) >> 16);
}
__device__ __forceinline__ float bf16f(short s) {
    return __uint_as_float((unsigned)(unsigned short)s << 16);
}

// ---------------- prep: softmaxes, fully parallel ----------------
__global__ __launch_bounds__(128) void k_prep(const float* __restrict__ a1w,
                                              const float* __restrict__ a2w,
                                              const float* __restrict__ opww,
                                              const float* __restrict__ chw,
                                              float* __restrict__ ws) {
    __shared__ float wred[2];
    int b = blockIdx.x;
    int j = threadIdx.x;  // 0..127
    if (b < 256) {
        int col = b & 127;
        const float* src = (b < 128) ? a1w : a2w;
        float* dst = ws + ((b < 128) ? OFF_S1T : OFF_S2T);
        float v = src[j * W128 + col];
        float m = v;
#pragma unroll
        for (int off = 32; off; off >>= 1) m = fmaxf(m, __shfl_xor(m, off));
        if ((j & 63) == 0) wred[j >> 6] = m;
        __syncthreads();
        m = fmaxf(wred[0], wred[1]);
        float e = expf(v - m);
        float s = e;
#pragma unroll
        for (int off = 32; off; off >>= 1) s += __shfl_xor(s, off);
        __syncthreads();
        if ((j & 63) == 0) wred[j >> 6] = s;
        __syncthreads();
        s = wred[0] + wred[1];
        dst[col * W128 + j] = e / s;
    } else {
        int i = j;
        float v[5], mx = -1e30f;
        for (int k = 0; k < 5; ++k) { v[k] = opww[i * 5 + k]; mx = fmaxf(mx, v[k]); }
        float s = 0.f;
        for (int k = 0; k < 5; ++k) { v[k] = expf(v[k] - mx); s += v[k]; }
        float inv = 1.0f / s;
        for (int k = 0; k < 5; ++k) ws[OFF_OPW + k * W128 + i] = v[k] * inv;
        float u[24]; mx = -1e30f;
        for (int k = 0; k < 24; ++k) { u[k] = chw[i * 24 + k]; mx = fmaxf(mx, u[k]); }
        s = 0.f;
        for (int k = 0; k < 24; ++k) { u[k] = expf(u[k] - mx); s += u[k]; }
        inv = 1.0f / s;
        for (int k = 0; k < 12; ++k) ws[OFF_WF + i * NREL + k] = u[k] * inv;
        for (int k = 0; k < 12; ++k) ws[OFF_WB + i * NREL + k] = u[12 + k] * inv;
    }
}

// ---------------- args: LDS-tiled, low redundancy ----------------
// grid (32 n-tiles, 8 w-tiles), 256 thr. Each block: stage inputs[128][32] once,
// compute arg1/arg2 for 16 w x 32 n.
__global__ __launch_bounds__(256) void k_args2(const float* __restrict__ inputs,
                                               float* __restrict__ ws,
                                               short* __restrict__ x2b) {
    __shared__ float lin[128 * 33];
    int t = threadIdx.x;
    int n0 = blockIdx.x * 32;
    int w0 = blockIdx.y * 16;
#pragma unroll
    for (int u = 0; u < 16; ++u) {
        int idx = t + u * 256;
        int j = idx >> 5, nn = idx & 31;
        lin[j * 33 + nn] = inputs[j * NNODE + n0 + nn];
    }
    __syncthreads();
    int nn = t & 31;
    int n = n0 + nn;
    int wA = w0 + (t >> 5);
    int wB = wA + 8;
    const float* s1A = ws + OFF_S1T + wA * W128;
    const float* s2A = ws + OFF_S2T + wA * W128;
    const float* s1B = ws + OFF_S1T + wB * W128;
    const float* s2B = ws + OFF_S2T + wB * W128;
    float a1A = 0.f, a2A = 0.f, a1B = 0.f, a2B = 0.f;
#pragma unroll 4
    for (int j = 0; j < W128; ++j) {
        float in = lin[j * 33 + nn];
        a1A = fmaf(s1A[j], in, a1A);
        a2A = fmaf(s2A[j], in, a2A);
        a1B = fmaf(s1B[j], in, a1B);
        a2B = fmaf(s2B[j], in, a2B);
    }
    ws[OFF_ARG1 + wA * NNODE + n] = a1A;
    ws[OFF_ARG2 + wA * NNODE + n] = a2A;
    ws[OFF_ARG1 + wB * NNODE + n] = a1B;
    ws[OFF_ARG2 + wB * NNODE + n] = a2B;
    x2b[wA * NNODE + n] = bf16t(a2A);
    x2b[wB * NNODE + n] = bf16t(a2B);
}

// ---------------- chain: one 64x64 db tile serves fwd AND bwd ----------------
// Block (bx=B-tile, by=A-tile): stages T = db[r][A][B] once per r.
//   fwd: out cols in B, contraction over A (transpose-read of T) -> partF[A][w][B]
//   bwd: out cols in A, contraction over B (row-read of T)       -> partB[B][w][A]
// Reg-prefetch of r+1's tile overlaps HBM latency with MFMA. wf/wb folded per r.
__global__ __launch_bounds__(512) void k_chain2(const float* __restrict__ db,
                                                const float* __restrict__ ws,
                                                const short* __restrict__ x2b,
                                                short* __restrict__ partF,
                                                short* __restrict__ partB) {
    __shared__ float dfs[64 * 65];   // T as f32 [a][b], stride 65 (2-way max on all patterns)
    const float* wf = ws + OFF_WF;
    const float* wb = ws + OFF_WB;

    int tid = threadIdx.x;
    int l   = tid & 63, wid = tid >> 6;
    int wm  = wid >> 1, wn = wid & 1;
    int l16 = l & 15,  lq = l >> 4;
    int B0  = blockIdx.x * 64;   // fwd out-col base / bwd contraction base
    int A0  = blockIdx.y * 64;   // fwd contraction base / bwd out-col base
    int cwl = wn * 32;

    // A-frags: X = arg2 bf16; fwd contracts over A-range, bwd over B-range
    bf16x8 afF[2][2], afB[2][2];
#pragma unroll
    for (int mi = 0; mi < 2; ++mi)
#pragma unroll
        for (int ks = 0; ks < 2; ++ks) {
            int w = wm * 32 + mi * 16 + l16;
            afF[mi][ks] = *(const bf16x8*)&x2b[w * NNODE + A0 + ks * 32 + lq * 8];
            afB[mi][ks] = *(const bf16x8*)&x2b[w * NNODE + B0 + ks * 32 + lq * 8];
        }

    f32x4 accF[2][2], accB[2][2];
#pragma unroll
    for (int mi = 0; mi < 2; ++mi)
#pragma unroll
        for (int ni = 0; ni < 2; ++ni) {
            accF[mi][ni] = (f32x4){0.f, 0.f, 0.f, 0.f};
            accB[mi][ni] = (f32x4){0.f, 0.f, 0.f, 0.f};
        }

    // per-thread stage slot: 8 consecutive floats of one tile row
    int row  = tid >> 3;
    int colb = (tid & 7) * 8;
    const float* gbase = db + (size_t)(A0 + row) * NNODE + B0 + colb;
    const size_t rstep = (size_t)NNODE * NNODE;

    float4 cur0 = *(const float4*)(gbase);
    float4 cur1 = *(const float4*)(gbase + 4);

#pragma unroll 2
    for (int r = 0; r < NREL; ++r) {
        // write staged regs -> LDS
        float* d = &dfs[row * 65 + colb];
        d[0] = cur0.x; d[1] = cur0.y; d[2] = cur0.z; d[3] = cur0.w;
        d[4] = cur1.x; d[5] = cur1.y; d[6] = cur1.z; d[7] = cur1.w;
        __syncthreads();
        // issue next tile's loads (in flight during MFMA)
        float4 nxt0 = cur0, nxt1 = cur1;
        if (r + 1 < NREL) {
            const float* g = gbase + (size_t)(r + 1) * rstep;
            nxt0 = *(const float4*)(g);
            nxt1 = *(const float4*)(g + 4);
        }

        f32x4 aF[2][2], aB[2][2];
#pragma unroll
        for (int mi = 0; mi < 2; ++mi)
#pragma unroll
            for (int ni = 0; ni < 2; ++ni) {
                aF[mi][ni] = (f32x4){0.f, 0.f, 0.f, 0.f};
                aB[mi][ni] = (f32x4){0.f, 0.f, 0.f, 0.f};
            }

#pragma unroll
        for (int ks = 0; ks < 2; ++ks) {
            bf16x8 bF[2], bB[2];
#pragma unroll
            for (int ni = 0; ni < 2; ++ni) {
                int col = cwl + ni * 16 + l16;
                int rb  = ks * 32 + lq * 8;
                // fwd B-frag: column `col` of T, 8 strided reads + pack
                float f0 = dfs[(rb + 0) * 65 + col];
                float f1 = dfs[(rb + 1) * 65 + col];
                float f2 = dfs[(rb + 2) * 65 + col];
                float f3 = dfs[(rb + 3) * 65 + col];
                float f4 = dfs[(rb + 4) * 65 + col];
                float f5 = dfs[(rb + 5) * 65 + col];
                float f6 = dfs[(rb + 6) * 65 + col];
                float f7 = dfs[(rb + 7) * 65 + col];
                int4 pk;
                pk.x = (int)((__float_as_uint(f1) & 0xFFFF0000u) | (__float_as_uint(f0) >> 16));
                pk.y = (int)((__float_as_uint(f3) & 0xFFFF0000u) | (__float_as_uint(f2) >> 16));
                pk.z = (int)((__float_as_uint(f5) & 0xFFFF0000u) | (__float_as_uint(f4) >> 16));
                pk.w = (int)((__float_as_uint(f7) & 0xFFFF0000u) | (__float_as_uint(f6) >> 16));
                bF[ni] = __builtin_bit_cast(bf16x8, pk);
                // bwd B-frag: row `col` of T, 8 consecutive reads + pack
                const float* rp = &dfs[col * 65 + rb];
                float g0 = rp[0], g1 = rp[1], g2 = rp[2], g3 = rp[3];
                float g4 = rp[4], g5 = rp[5], g6 = rp[6], g7 = rp[7];
                int4 qk;
                qk.x = (int)((__float_as_uint(g1) & 0xFFFF0000u) | (__float_as_uint(g0) >> 16));
                qk.y = (int)((__float_as_uint(g3) & 0xFFFF0000u) | (__float_as_uint(g2) >> 16));
                qk.z = (int)((__float_as_uint(g5) & 0xFFFF0000u) | (__float_as_uint(g4) >> 16));
                qk.w = (int)((__float_as_uint(g7) & 0xFFFF0000u) | (__float_as_uint(g6) >> 16));
                bB[ni] = __builtin_bit_cast(bf16x8, qk);
            }
#pragma unroll
            for (int mi = 0; mi < 2; ++mi)
#pragma unroll
                for (int ni = 0; ni < 2; ++ni) {
                    aF[mi][ni] = __builtin_amdgcn_mfma_f32_16x16x32_bf16(
                        afF[mi][ks], bF[ni], aF[mi][ni], 0, 0, 0);
                    aB[mi][ni] = __builtin_amdgcn_mfma_f32_16x16x32_bf16(
                        afB[mi][ks], bB[ni], aB[mi][ni], 0, 0, 0);
                }
        }
        __syncthreads();

        // fold per-(w,r) chain weights
#pragma unroll
        for (int mi = 0; mi < 2; ++mi)
#pragma unroll
            for (int v = 0; v < 4; ++v) {
                int w = wm * 32 + mi * 16 + lq * 4 + v;
                float wfv = wf[w * NREL + r];
                float wbv = wb[w * NREL + r];
#pragma unroll
                for (int ni = 0; ni < 2; ++ni) {
                    accF[mi][ni][v] += wfv * aF[mi][ni][v];
                    accB[mi][ni][v] += wbv * aB[mi][ni][v];
                }
            }
        cur0 = nxt0; cur1 = nxt1;
    }

    // write bf16 partial slices: partF[A-slice][w][B-cols], partB[B-slice][w][A-cols]
#pragma unroll
    for (int mi = 0; mi < 2; ++mi)
#pragma unroll
        for (int ni = 0; ni < 2; ++ni) {
            int cF = B0 + cwl + ni * 16 + l16;
            int cA = A0 + cwl + ni * 16 + l16;
#pragma unroll
            for (int v = 0; v < 4; ++v) {
                int w = wm * 32 + mi * 16 + lq * 4 + v;
                partF[((size_t)blockIdx.y * W128 + w) * NNODE + cF] = bf16t(accF[mi][ni][v]);
                partB[((size_t)blockIdx.x * W128 + w) * NNODE + cA] = bf16t(accB[mi][ni][v]);
            }
        }
}

// ---------------- reduce 32 bf16 slices + final op combine ----------------
__global__ __launch_bounds__(256) void k_reduce2(const float* __restrict__ ws,
                                                 const short* __restrict__ partF,
                                                 const short* __restrict__ partB,
                                                 float* __restrict__ out) {
    int e0 = (blockIdx.x * 256 + threadIdx.x) * 4;  // 4 consecutive elems, same w
    int w = e0 >> 10;
    float ch0 = 0.f, ch1 = 0.f, ch2 = 0.f, ch3 = 0.f;
#pragma unroll
    for (int s = 0; s < 16; ++s) {
        short4v pf = *(const short4v*)&partF[(size_t)s * (W128 * NNODE) + e0];
        short4v pb = *(const short4v*)&partB[(size_t)s * (W128 * NNODE) + e0];
        ch0 += bf16f(pf[0]) + bf16f(pb[0]);
        ch1 += bf16f(pf[1]) + bf16f(pb[1]);
        ch2 += bf16f(pf[2]) + bf16f(pb[2]);
        ch3 += bf16f(pf[3]) + bf16f(pb[3]);
    }
    float4 a1 = *(const float4*)&ws[OFF_ARG1 + e0];
    float4 a2 = *(const float4*)&ws[OFF_ARG2 + e0];
    float o0 = ws[OFF_OPW + 0 * W128 + w];
    float o1 = ws[OFF_OPW + 1 * W128 + w];
    float o2 = ws[OFF_OPW + 2 * W128 + w];
    float o3 = ws[OFF_OPW + 3 * W128 + w];
    float o4 = ws[OFF_OPW + 4 * W128 + w];
    float a1v[4] = {a1.x, a1.y, a1.z, a1.w};
    float a2v[4] = {a2.x, a2.y, a2.z, a2.w};
    float chv[4] = {ch0, ch1, ch2, ch3};
    float ov[4];
#pragma unroll
    for (int j = 0; j < 4; ++j) {
        float p = a1v[j] * a2v[j];
        ov[j] = o0 * a2v[j] + o1 * p + o2 * (a1v[j] + a2v[j] - p)
              + o3 * (1.0f - expf(-chv[j])) + o4 * (1.0f - a1v[j]);
    }
    float4 o = {ov[0], ov[1], ov[2], ov[3]};
    *(float4*)&out[e0] = o;
}

extern "C" void kernel_launch(void* const* d_in, const int* in_sizes, int n_in,
                              void* d_out, int out_size, void* d_ws, size_t ws_size,
                              hipStream_t stream) {
    const float* inputs = (const float*)d_in[0];
    const float* db     = (const float*)d_in[1];
    const float* a1w    = (const float*)d_in[2];
    const float* a2w    = (const float*)d_in[3];
    const float* opww   = (const float*)d_in[4];
    const float* chw    = (const float*)d_in[5];
    float* ws  = (float*)d_ws;
    float* out = (float*)d_out;
    short* x2b   = (short*)(ws + OFF_ARG2B);
    short* partF = (short*)(ws + OFF_PART);
    short* partB = partF + (size_t)16 * W128 * NNODE;

    hipLaunchKernelGGL(k_prep, dim3(257), dim3(128), 0, stream, a1w, a2w, opww, chw, ws);
    hipLaunchKernelGGL(k_args2, dim3(32, 8), dim3(256), 0, stream, inputs, ws, x2b);
    hipLaunchKernelGGL(k_chain2, dim3(16, 16), dim3(512), 0, stream,
                       db, ws, x2b, partF, partB);
    hipLaunchKernelGGL(k_reduce2, dim3(128), dim3(256), 0, stream, ws, partF, partB, out);
}

// Round 10
// 41.228 us; speedup vs baseline: 4.4427x; 1.1433x over previous
//
#include <hip/hip_runtime.h>
#include <math.h>

#define W128  128
#define NNODE 1024
#define NREL  12
#define TS    72        // bf16 LDS tile stride (144B rows: 16B-aligned, 2-way banks)

// ws layout (float offsets)
#define OFF_S1T   0         // 128x128
#define OFF_S2T   16384     // 128x128
#define OFF_OPW   32768     // 5x128
#define OFF_WF    33408     // 128x12
#define OFF_WB    34944     // 128x12
#define OFF_ARG1  36480     // 128x1024 f32
#define OFF_ARG2  167552    // 128x1024 f32
#define OFF_ARG2B 298624    // 128x1024 bf16
#define OFF_PART  364160    // partF 16x1024x128 bf16, then partB same

typedef short bf16x8 __attribute__((ext_vector_type(8)));
typedef short short4v __attribute__((ext_vector_type(4)));
typedef float f32x4  __attribute__((ext_vector_type(4)));

__device__ __forceinline__ short bf16t(float x) {
    return (short)(__float_as_uint(x) >> 16);
}
__device__ __forceinline__ float bf16f(short s) {
    return __uint_as_float((unsigned)(unsigned short)s << 16);
}
__device__ __forceinline__ unsigned pk2(float lo, float hi) {
    return (__float_as_uint(hi) & 0xFFFF0000u) | (__float_as_uint(lo) >> 16);
}

// ---------------- prep: softmaxes, fully parallel ----------------
__global__ __launch_bounds__(128) void k_prep(const float* __restrict__ a1w,
                                              const float* __restrict__ a2w,
                                              const float* __restrict__ opww,
                                              const float* __restrict__ chw,
                                              float* __restrict__ ws) {
    __shared__ float wred[2];
    int b = blockIdx.x;
    int j = threadIdx.x;  // 0..127
    if (b < 256) {
        int col = b & 127;
        const float* src = (b < 128) ? a1w : a2w;
        float* dst = ws + ((b < 128) ? OFF_S1T : OFF_S2T);
        float v = src[j * W128 + col];
        float m = v;
#pragma unroll
        for (int off = 32; off; off >>= 1) m = fmaxf(m, __shfl_xor(m, off));
        if ((j & 63) == 0) wred[j >> 6] = m;
        __syncthreads();
        m = fmaxf(wred[0], wred[1]);
        float e = expf(v - m);
        float s = e;
#pragma unroll
        for (int off = 32; off; off >>= 1) s += __shfl_xor(s, off);
        __syncthreads();
        if ((j & 63) == 0) wred[j >> 6] = s;
        __syncthreads();
        s = wred[0] + wred[1];
        dst[col * W128 + j] = e / s;
    } else {
        int i = j;
        float v[5], mx = -1e30f;
        for (int k = 0; k < 5; ++k) { v[k] = opww[i * 5 + k]; mx = fmaxf(mx, v[k]); }
        float s = 0.f;
        for (int k = 0; k < 5; ++k) { v[k] = expf(v[k] - mx); s += v[k]; }
        float inv = 1.0f / s;
        for (int k = 0; k < 5; ++k) ws[OFF_OPW + k * W128 + i] = v[k] * inv;
        float u[24]; mx = -1e30f;
        for (int k = 0; k < 24; ++k) { u[k] = chw[i * 24 + k]; mx = fmaxf(mx, u[k]); }
        s = 0.f;
        for (int k = 0; k < 24; ++k) { u[k] = expf(u[k] - mx); s += u[k]; }
        inv = 1.0f / s;
        for (int k = 0; k < 12; ++k) ws[OFF_WF + i * NREL + k] = u[k] * inv;
        for (int k = 0; k < 12; ++k) ws[OFF_WB + i * NREL + k] = u[12 + k] * inv;
    }
}

// ---------------- args: LDS-tiled ----------------
__global__ __launch_bounds__(256) void k_args2(const float* __restrict__ inputs,
                                               float* __restrict__ ws,
                                               short* __restrict__ x2b) {
    __shared__ float lin[128 * 33];
    int t = threadIdx.x;
    int n0 = blockIdx.x * 32;
    int w0 = blockIdx.y * 16;
#pragma unroll
    for (int u = 0; u < 16; ++u) {
        int idx = t + u * 256;
        int j = idx >> 5, nn = idx & 31;
        lin[j * 33 + nn] = inputs[j * NNODE + n0 + nn];
    }
    __syncthreads();
    int nn = t & 31;
    int n = n0 + nn;
    int wA = w0 + (t >> 5);
    int wB = wA + 8;
    const float* s1A = ws + OFF_S1T + wA * W128;
    const float* s2A = ws + OFF_S2T + wA * W128;
    const float* s1B = ws + OFF_S1T + wB * W128;
    const float* s2B = ws + OFF_S2T + wB * W128;
    float a1A = 0.f, a2A = 0.f, a1B = 0.f, a2B = 0.f;
#pragma unroll 4
    for (int j = 0; j < W128; ++j) {
        float in = lin[j * 33 + nn];
        a1A = fmaf(s1A[j], in, a1A);
        a2A = fmaf(s2A[j], in, a2A);
        a1B = fmaf(s1B[j], in, a1B);
        a2B = fmaf(s2B[j], in, a2B);
    }
    ws[OFF_ARG1 + wA * NNODE + n] = a1A;
    ws[OFF_ARG2 + wA * NNODE + n] = a2A;
    ws[OFF_ARG1 + wB * NNODE + n] = a1B;
    ws[OFF_ARG2 + wB * NNODE + n] = a2B;
    x2b[wA * NNODE + n] = bf16t(a2A);
    x2b[wB * NNODE + n] = bf16t(a2B);
}

// ---------------- chain: bf16 tiles packed once at staging, b128-only reads --
// Output orientation [node][w]: m=node, n=w, k=node.
//   bwd: D[a][w] = sum_b Tf[a][b] * x2b[w][B0+b]   (A = straight tile Tf)
//   fwd: D[c][w] = sum_a Tt[c][a] * x2b[w][A0+a]   (A = transpose tile Tt)
// B-frags (x2b) are loop-invariant registers. A-frags: 8 ds_read_b128/wave/r.
// Staging: each thread loads a 2-row x 4-col f32 patch once, writes Tf (2xb64)
// and Tt (4xb32, transposed pairs). Register prefetch of r+1's patch.
__global__ __launch_bounds__(512) void k_chain3(const float* __restrict__ db,
                                                const float* __restrict__ ws,
                                                const short* __restrict__ x2b,
                                                short* __restrict__ partF,
                                                short* __restrict__ partB) {
    __shared__ __align__(16) short Tf[64 * TS];  // T[a][b]
    __shared__ __align__(16) short Tt[64 * TS];  // T^T[c][a]
    const float* wf = ws + OFF_WF;
    const float* wb = ws + OFF_WB;

    int tid = threadIdx.x;
    int l   = tid & 63, wid = tid >> 6;
    int wm  = wid >> 2;          // 0..1 : node-half (m)
    int wn  = wid & 3;           // 0..3 : w-quarter (n)
    int l16 = l & 15, lq = l >> 4;
    int B0  = blockIdx.x * 64;   // fwd out-node range / bwd contraction range
    int A0  = blockIdx.y * 64;   // bwd out-node range / fwd contraction range

    // B-frags from x2b (loop-invariant): [ni][ks]
    bf16x8 bfF[2][2], bfB[2][2];
#pragma unroll
    for (int ni = 0; ni < 2; ++ni)
#pragma unroll
        for (int ks = 0; ks < 2; ++ks) {
            int w = wn * 32 + ni * 16 + l16;
            bfF[ni][ks] = *(const bf16x8*)&x2b[w * NNODE + A0 + ks * 32 + lq * 8];
            bfB[ni][ks] = *(const bf16x8*)&x2b[w * NNODE + B0 + ks * 32 + lq * 8];
        }

    f32x4 accF[2][2], accB[2][2];
#pragma unroll
    for (int mi = 0; mi < 2; ++mi)
#pragma unroll
        for (int ni = 0; ni < 2; ++ni) {
            accF[mi][ni] = (f32x4){0.f, 0.f, 0.f, 0.f};
            accB[mi][ni] = (f32x4){0.f, 0.f, 0.f, 0.f};
        }

    // staging patch: rows a0,a0+1 (global A0+), cols c0..c0+3 (global B0+)
    int a0 = 2 * (tid >> 4);        // 0..62
    int c0 = 4 * (tid & 15);        // 0..60
    const float* gbase = db + (size_t)(A0 + a0) * NNODE + B0 + c0;
    const size_t rstep = (size_t)NNODE * NNODE;

    float4 g0 = *(const float4*)(gbase);
    float4 g1 = *(const float4*)(gbase + NNODE);

#pragma unroll 2
    for (int r = 0; r < NREL; ++r) {
        // ---- stage packed tiles ----
        // Tf rows a0, a0+1 (each 4 bf16 = one b64)
        uint2 p0 = {pk2(g0.x, g0.y), pk2(g0.z, g0.w)};
        uint2 p1 = {pk2(g1.x, g1.y), pk2(g1.z, g1.w)};
        *(uint2*)&Tf[a0 * TS + c0]       = p0;
        *(uint2*)&Tf[(a0 + 1) * TS + c0] = p1;
        // Tt rows c0..c0+3, col pair (a0,a0+1) (each one b32)
        *(unsigned*)&Tt[(c0 + 0) * TS + a0] = pk2(g0.x, g1.x);
        *(unsigned*)&Tt[(c0 + 1) * TS + a0] = pk2(g0.y, g1.y);
        *(unsigned*)&Tt[(c0 + 2) * TS + a0] = pk2(g0.z, g1.z);
        *(unsigned*)&Tt[(c0 + 3) * TS + a0] = pk2(g0.w, g1.w);
        __syncthreads();

        // prefetch next r's patch (in flight during MFMA)
        float4 n0v = g0, n1v = g1;
        if (r + 1 < NREL) {
            const float* g = gbase + (size_t)(r + 1) * rstep;
            n0v = *(const float4*)(g);
            n1v = *(const float4*)(g + NNODE);
        }

        f32x4 tF[2][2], tB[2][2];
#pragma unroll
        for (int mi = 0; mi < 2; ++mi)
#pragma unroll
            for (int ni = 0; ni < 2; ++ni) {
                tF[mi][ni] = (f32x4){0.f, 0.f, 0.f, 0.f};
                tB[mi][ni] = (f32x4){0.f, 0.f, 0.f, 0.f};
            }

#pragma unroll
        for (int ks = 0; ks < 2; ++ks) {
            bf16x8 AF[2], AB[2];
#pragma unroll
            for (int mi = 0; mi < 2; ++mi) {
                int row = wm * 32 + mi * 16 + l16;
                int off = ks * 32 + lq * 8;
                AF[mi] = *(const bf16x8*)&Tt[row * TS + off];
                AB[mi] = *(const bf16x8*)&Tf[row * TS + off];
            }
#pragma unroll
            for (int mi = 0; mi < 2; ++mi)
#pragma unroll
                for (int ni = 0; ni < 2; ++ni) {
                    tF[mi][ni] = __builtin_amdgcn_mfma_f32_16x16x32_bf16(
                        AF[mi], bfF[ni][ks], tF[mi][ni], 0, 0, 0);
                    tB[mi][ni] = __builtin_amdgcn_mfma_f32_16x16x32_bf16(
                        AB[mi], bfB[ni][ks], tB[mi][ni], 0, 0, 0);
                }
        }
        __syncthreads();

        // fold per-(w,r) chain weights (w is the lane column now)
#pragma unroll
        for (int ni = 0; ni < 2; ++ni) {
            int w = wn * 32 + ni * 16 + l16;
            float wfv = wf[w * NREL + r];
            float wbv = wb[w * NREL + r];
#pragma unroll
            for (int mi = 0; mi < 2; ++mi)
#pragma unroll
                for (int v = 0; v < 4; ++v) {
                    accF[mi][ni][v] += wfv * tF[mi][ni][v];
                    accB[mi][ni][v] += wbv * tB[mi][ni][v];
                }
        }
        g0 = n0v; g1 = n1v;
    }

    // write bf16 partials, [node][w]-major
    // partF slice by (A0-tile): node = B0 + m ;  partB slice bx: node = A0 + m
#pragma unroll
    for (int mi = 0; mi < 2; ++mi)
#pragma unroll
        for (int v = 0; v < 4; ++v) {
            int m = wm * 32 + mi * 16 + lq * 4 + v;
#pragma unroll
            for (int ni = 0; ni < 2; ++ni) {
                int w = wn * 32 + ni * 16 + l16;
                partF[(size_t)blockIdx.y * (NNODE * W128) + (B0 + m) * W128 + w]
                    = bf16t(accF[mi][ni][v]);
                partB[(size_t)blockIdx.x * (NNODE * W128) + (A0 + m) * W128 + w]
                    = bf16t(accB[mi][ni][v]);
            }
        }
}

// ---------------- reduce 32 slices ([n][w]) + op combine, LDS transpose -----
// grid (16 n-tiles x 8 w-tiles), 256 thr. Block tile: 64 n x 16 w.
__global__ __launch_bounds__(256) void k_reduce3(const float* __restrict__ ws,
                                                 const short* __restrict__ partF,
                                                 const short* __restrict__ partB,
                                                 float* __restrict__ out) {
    __shared__ float chs[64 * 17];
    int t = threadIdx.x;
    int n0 = blockIdx.x * 64;
    int w0 = blockIdx.y * 16;
    // phase 1: reduce slices; thread owns (n_loc, 4 w's)
    {
        int n_loc = t >> 2;
        int wq = (t & 3) * 4;
        size_t base = (size_t)(n0 + n_loc) * W128 + w0 + wq;
        float c0 = 0.f, c1 = 0.f, c2 = 0.f, c3 = 0.f;
#pragma unroll
        for (int s = 0; s < 16; ++s) {
            short4v pf = *(const short4v*)&partF[(size_t)s * (NNODE * W128) + base];
            short4v pb = *(const short4v*)&partB[(size_t)s * (NNODE * W128) + base];
            c0 += bf16f(pf[0]) + bf16f(pb[0]);
            c1 += bf16f(pf[1]) + bf16f(pb[1]);
            c2 += bf16f(pf[2]) + bf16f(pb[2]);
            c3 += bf16f(pf[3]) + bf16f(pb[3]);
        }
        chs[n_loc * 17 + wq + 0] = c0;
        chs[n_loc * 17 + wq + 1] = c1;
        chs[n_loc * 17 + wq + 2] = c2;
        chs[n_loc * 17 + wq + 3] = c3;
    }
    __syncthreads();
    // phase 2: thread owns (w_loc, 4 n's); all global IO coalesced
    {
        int w_loc = t >> 4;          // 0..15
        int n4 = (t & 15) * 4;       // 0..60
        int w = w0 + w_loc;
        float ch[4];
#pragma unroll
        for (int j = 0; j < 4; ++j) ch[j] = chs[(n4 + j) * 17 + w_loc];
        float4 a1 = *(const float4*)&ws[OFF_ARG1 + w * NNODE + n0 + n4];
        float4 a2 = *(const float4*)&ws[OFF_ARG2 + w * NNODE + n0 + n4];
        float o0 = ws[OFF_OPW + 0 * W128 + w];
        float o1 = ws[OFF_OPW + 1 * W128 + w];
        float o2 = ws[OFF_OPW + 2 * W128 + w];
        float o3 = ws[OFF_OPW + 3 * W128 + w];
        float o4 = ws[OFF_OPW + 4 * W128 + w];
        float a1v[4] = {a1.x, a1.y, a1.z, a1.w};
        float a2v[4] = {a2.x, a2.y, a2.z, a2.w};
        float ov[4];
#pragma unroll
        for (int j = 0; j < 4; ++j) {
            float p = a1v[j] * a2v[j];
            ov[j] = o0 * a2v[j] + o1 * p + o2 * (a1v[j] + a2v[j] - p)
                  + o3 * (1.0f - expf(-ch[j])) + o4 * (1.0f - a1v[j]);
        }
        float4 o = {ov[0], ov[1], ov[2], ov[3]};
        *(float4*)&out[w * NNODE + n0 + n4] = o;
    }
}

extern "C" void kernel_launch(void* const* d_in, const int* in_sizes, int n_in,
                              void* d_out, int out_size, void* d_ws, size_t ws_size,
                              hipStream_t stream) {
    const float* inputs = (const float*)d_in[0];
    const float* db     = (const float*)d_in[1];
    const float* a1w    = (const float*)d_in[2];
    const float* a2w    = (const float*)d_in[3];
    const float* opww   = (const float*)d_in[4];
    const float* chw    = (const float*)d_in[5];
    float* ws  = (float*)d_ws;
    float* out = (float*)d_out;
    short* x2b   = (short*)(ws + OFF_ARG2B);
    short* partF = (short*)(ws + OFF_PART);
    short* partB = partF + (size_t)16 * NNODE * W128;

    hipLaunchKernelGGL(k_prep, dim3(257), dim3(128), 0, stream, a1w, a2w, opww, chw, ws);
    hipLaunchKernelGGL(k_args2, dim3(32, 8), dim3(256), 0, stream, inputs, ws, x2b);
    hipLaunchKernelGGL(k_chain3, dim3(16, 16), dim3(512), 0, stream,
                       db, ws, x2b, partF, partB);
    hipLaunchKernelGGL(k_reduce3, dim3(16, 8), dim3(256), 0, stream,
                       ws, partF, partB, out);
}